// Round 3
// baseline (194.052 us; speedup 1.0000x reference)
//
#include <hip/hip_runtime.h>
#include <hip/hip_bf16.h>

using bf16x8 = __attribute__((ext_vector_type(8))) __bf16;
using f32x4  = __attribute__((ext_vector_type(4))) float;
using i32x4  = __attribute__((ext_vector_type(4))) int;

#define BM 128
#define BN 64
#define BK 64
#define NTHR 512   // 8 waves: 4 (M) x 2 (N); wave tile 32x32

// out[M,N] = x[M,K] @ W^T + bias,  W[n,k] = qw[n,k] * scales[n, k/GS]
__global__ __launch_bounds__(NTHR, 6)
void gptq_gemm(const float* __restrict__ x, const int* __restrict__ qw,
               const float* __restrict__ scales, const float* __restrict__ bias,
               float* __restrict__ out, int M, int N, int K, int NG, int GS, int gy) {
  __shared__ __bf16 lds_a[2][BM * BK];   // 32 KiB
  __shared__ __bf16 lds_b[2][BN * BK];   // 16 KiB

  const int tid  = threadIdx.x;
  const int lane = tid & 63;
  const int wave = tid >> 6;
  const int wr   = wave >> 1;     // 0..3
  const int wc   = wave & 1;      // 0..1

  // by-fast ordering: 4 consecutive blocks share one qweight panel (L3 reuse)
  const int bx = blockIdx.x / gy;
  const int by = blockIdx.x % gy;
  const int tileM = by * BM;
  const int tileN = bx * BN;

  const int l15 = lane & 15;
  const int l4  = lane >> 4;      // 0..3

  // staging coords (per thread): same slot for all units
  const int srow = tid >> 3;      // 0..63
  const int sc8  = tid & 7;
  const int slotS = sc8 ^ (srow & 7);

  f32x4 acc[2][2];
#pragma unroll
  for (int m = 0; m < 2; ++m)
#pragma unroll
    for (int n = 0; n < 2; ++n)
      acc[m][n] = (f32x4)0.0f;

  const float* xA0 = x + (size_t)(tileM + srow) * K + sc8 * 8;
  const float* xA1 = x + (size_t)(tileM + 64 + srow) * K + sc8 * 8;
  const int    gnB = tileN + srow;
  const int*   qB  = qw + (size_t)gnB * K + sc8 * 8;
  const float* sB  = scales + (size_t)gnB * NG;

  f32x4 va[2][2]; i32x4 vb[2]; float vs;

  auto issueLoads = [&](int k0) {
    const f32x4* a0 = reinterpret_cast<const f32x4*>(xA0 + k0);
    const f32x4* a1 = reinterpret_cast<const f32x4*>(xA1 + k0);
    va[0][0] = a0[0]; va[0][1] = a0[1];
    va[1][0] = a1[0]; va[1][1] = a1[1];
    const i32x4* b = reinterpret_cast<const i32x4*>(qB + k0);
    vb[0] = b[0]; vb[1] = b[1];
    vs = sB[k0 / GS];
  };
  auto stageWrite = [&](int buf) {
#pragma unroll
    for (int i = 0; i < 2; ++i) {
      bf16x8 wa;
      wa[0] = (__bf16)va[i][0][0]; wa[1] = (__bf16)va[i][0][1];
      wa[2] = (__bf16)va[i][0][2]; wa[3] = (__bf16)va[i][0][3];
      wa[4] = (__bf16)va[i][1][0]; wa[5] = (__bf16)va[i][1][1];
      wa[6] = (__bf16)va[i][1][2]; wa[7] = (__bf16)va[i][1][3];
      *reinterpret_cast<bf16x8*>(&lds_a[buf][(i * 64 + srow) * BK + slotS * 8]) = wa;
    }
    bf16x8 wb;
    wb[0] = (__bf16)((float)vb[0][0] * vs); wb[1] = (__bf16)((float)vb[0][1] * vs);
    wb[2] = (__bf16)((float)vb[0][2] * vs); wb[3] = (__bf16)((float)vb[0][3] * vs);
    wb[4] = (__bf16)((float)vb[1][0] * vs); wb[5] = (__bf16)((float)vb[1][1] * vs);
    wb[6] = (__bf16)((float)vb[1][2] * vs); wb[7] = (__bf16)((float)vb[1][3] * vs);
    *reinterpret_cast<bf16x8*>(&lds_b[buf][srow * BK + slotS * 8]) = wb;
  };

  auto mfmaTile = [&](int buf) {
#pragma unroll
    for (int kk = 0; kk < BK; kk += 32) {
      bf16x8 af[2], bfr[2];
      const int c8 = (kk >> 3) + l4;
#pragma unroll
      for (int m = 0; m < 2; ++m) {
        int row  = wr * 32 + m * 16 + l15;
        int slot = c8 ^ (row & 7);
        af[m] = *reinterpret_cast<const bf16x8*>(&lds_a[buf][row * BK + slot * 8]);
      }
#pragma unroll
      for (int n = 0; n < 2; ++n) {
        int row  = wc * 32 + n * 16 + l15;
        int slot = c8 ^ (row & 7);
        bfr[n] = *reinterpret_cast<const bf16x8*>(&lds_b[buf][row * BK + slot * 8]);
      }
#pragma unroll
      for (int m = 0; m < 2; ++m)
#pragma unroll
        for (int n = 0; n < 2; ++n)
          acc[m][n] =
              __builtin_amdgcn_mfma_f32_16x16x32_bf16(af[m], bfr[n], acc[m][n], 0, 0, 0);
    }
  };

  // prologue: stage tile 0
  issueLoads(0);
  stageWrite(0);
  __syncthreads();

  int cur = 0;
  for (int k0 = 0; k0 < K - BK; k0 += BK) {
    issueLoads(k0 + BK);                    // issue next-tile globals EARLY
    __builtin_amdgcn_sched_barrier(0);      // pin: loads above, compute below
    mfmaTile(cur);                          // ds_read + MFMA on current buf
    stageWrite(cur ^ 1);                    // vmcnt wait happens here
    __syncthreads();
    cur ^= 1;
  }
  mfmaTile(cur);                            // last tile, no prefetch

  // ---- epilogue: D row = l4*4 + r, col = l15 ----
#pragma unroll
  for (int n = 0; n < 2; ++n) {
    int col  = tileN + wc * 32 + n * 16 + l15;
    float bv = bias[col];
#pragma unroll
    for (int m = 0; m < 2; ++m) {
      int rbase = tileM + wr * 32 + m * 16 + l4 * 4;
#pragma unroll
      for (int r = 0; r < 4; ++r)
        out[(size_t)(rbase + r) * N + col] = acc[m][n][r] + bv;
    }
  }
}

extern "C" void kernel_launch(void* const* d_in, const int* in_sizes, int n_in,
                              void* d_out, int out_size, void* d_ws, size_t ws_size,
                              hipStream_t stream) {
  const float* x      = (const float*)d_in[0];
  const int*   qw     = (const int*)d_in[1];
  const float* scales = (const float*)d_in[2];
  const float* bias   = (const float*)d_in[3];
  float*       out    = (float*)d_out;

  const int OUT = in_sizes[3];            // 11008
  const int IN  = in_sizes[1] / OUT;      // 4096
  const int M   = in_sizes[0] / IN;       // 512
  const int NG  = in_sizes[2] / OUT;      // 32
  const int GS  = IN / NG;                // 128

  const int gx = OUT / BN;                // 172
  const int gy = M / BM;                  // 4
  gptq_gemm<<<gx * gy, NTHR, 0, stream>>>(x, qw, scales, bias, out, M, OUT, IN, NG, GS, gy);
}